// Round 8
// baseline (151.916 us; speedup 1.0000x reference)
//
#include <hip/hip_runtime.h>
#include <cstdint>

typedef short bf16x8 __attribute__((ext_vector_type(8)));
typedef float f32x4 __attribute__((ext_vector_type(4)));
typedef _Float16 half2v __attribute__((ext_vector_type(2)));

__device__ __forceinline__ unsigned short f2bf(float f) {
  unsigned u = __builtin_bit_cast(unsigned, f);
  u += 0x7fffu + ((u >> 16) & 1u);  // RNE
  return (unsigned short)(u >> 16);
}
__device__ __forceinline__ unsigned pkh2(float a, float b) {
  return __builtin_bit_cast(unsigned, __builtin_amdgcn_cvt_pkrtz(a, b));
}
__device__ __forceinline__ float fast_tanh(float x) {
  float e = __builtin_amdgcn_exp2f(x * 2.885390081777927f);
  return 1.0f - 2.0f * __builtin_amdgcn_rcpf(e + 1.0f);
}
// packed fp16 fma: c += a*b (v_pk_fma_f16)
__device__ __forceinline__ half2v fma2(unsigned a, unsigned b, half2v c) {
#if __has_builtin(__builtin_elementwise_fma)
  return __builtin_elementwise_fma(__builtin_bit_cast(half2v, a),
                                   __builtin_bit_cast(half2v, b), c);
#else
  return __builtin_bit_cast(half2v, a) * __builtin_bit_cast(half2v, b) + c;
#endif
}

// ---------------------------------------------------------------------------
// Stage 1: per-(ks,bt,co) partial GEMM (bf16 MFMA), channel-last partials.
// Block 0 additionally builds wtab2: w3 as bf16 B-fragments,
// [co 16 (>=4 zero)][kdkh 16][kw 4][cio-pair 4] dwords (16 KB).
// ---------------------------------------------------------------------------
template <int ITERS>
__global__ __launch_bounds__(256) void k_stage1(const float* __restrict__ x,
                                                const float* __restrict__ w1,
                                                const float* __restrict__ w3,
                                                float* __restrict__ part,
                                                unsigned* __restrict__ wtab2) {
  __shared__ __align__(16) char lds_raw[64 * 65 * 4];
  unsigned short* As = (unsigned short*)lds_raw;           // 64 rows * 40 hw
  unsigned short* Bs = (unsigned short*)(lds_raw + 5120);  // 64 rows * 40 hw
  float* Cs = (float*)lds_raw;                             // 64 x 65 fp32

  const int tid = threadIdx.x;
  if (blockIdx.x == 0) {
    for (int d = tid; d < 4096; d += 256) {
      int cp = d & 3, kw = (d >> 2) & 3, kdkh = (d >> 4) & 15, co = d >> 8;
      unsigned v = 0u;
      if (co < 4) {
        int off = ((kdkh >> 2) << 4) + ((kdkh & 3) << 2) + kw;
        float w0 = w3[((co << 3) + (cp << 1)) * 64 + off];
        float w1v = w3[((co << 3) + (cp << 1) + 1) * 64 + off];
        v = (unsigned)f2bf(w0) | ((unsigned)f2bf(w1v) << 16);
      }
      wtab2[d] = v;
    }
  }

  const int ks = blockIdx.x >> 7;
  const int bt = (blockIdx.x >> 3) & 15;
  const int co = blockIdx.x & 7;
  const int w = tid >> 6, lane = tid & 63, lm = lane & 15, q = lane >> 4;
  const int rrow = tid & 63, kgr = tid >> 6;

  f32x4 acc[4];
#pragma unroll
  for (int i = 0; i < 4; ++i) acc[i] = (f32x4){0.f, 0.f, 0.f, 0.f};

  const float* gA = x + (bt << 16) + ((size_t)(ks * ITERS * 32) << 6);
  const float* gB = w1 + (co << 6) + (size_t)(ks * ITERS * 32) * 512;

  float va[2][8], vb[2][8];
#define S1_LOAD(buf, it)                            \
  {                                                 \
    const int kb = (it) * 32 + (kgr << 3);          \
    _Pragma("unroll") for (int j = 0; j < 8; ++j) { \
      va[buf][j] = gA[((kb + j) << 6) | rrow];      \
      vb[buf][j] = gB[(kb + j) * 512 + rrow];       \
    }                                               \
  }
  S1_LOAD(0, 0);
#pragma unroll
  for (int it = 0; it < ITERS; ++it) {
    const int cur = it & 1;
    if (it + 1 < ITERS) S1_LOAD(cur ^ 1, it + 1);
    uint4 pa, pb;
    pa.x = f2bf(va[cur][0]) | ((unsigned)f2bf(va[cur][1]) << 16);
    pa.y = f2bf(va[cur][2]) | ((unsigned)f2bf(va[cur][3]) << 16);
    pa.z = f2bf(va[cur][4]) | ((unsigned)f2bf(va[cur][5]) << 16);
    pa.w = f2bf(va[cur][6]) | ((unsigned)f2bf(va[cur][7]) << 16);
    pb.x = f2bf(vb[cur][0]) | ((unsigned)f2bf(vb[cur][1]) << 16);
    pb.y = f2bf(vb[cur][2]) | ((unsigned)f2bf(vb[cur][3]) << 16);
    pb.z = f2bf(vb[cur][4]) | ((unsigned)f2bf(vb[cur][5]) << 16);
    pb.w = f2bf(vb[cur][6]) | ((unsigned)f2bf(vb[cur][7]) << 16);
    *(uint4*)&As[rrow * 40 + (kgr << 3)] = pa;
    *(uint4*)&Bs[rrow * 40 + (kgr << 3)] = pb;
    __syncthreads();
    bf16x8 a = *(const bf16x8*)&As[((w << 4) + lm) * 40 + (q << 3)];
#pragma unroll
    for (int nf = 0; nf < 4; ++nf) {
      bf16x8 b = *(const bf16x8*)&Bs[((nf << 4) + lm) * 40 + (q << 3)];
      acc[nf] = __builtin_amdgcn_mfma_f32_16x16x32_bf16(a, b, acc[nf], 0, 0, 0);
    }
    __syncthreads();
  }
#undef S1_LOAD
#pragma unroll
  for (int nf = 0; nf < 4; ++nf)
#pragma unroll
    for (int r = 0; r < 4; ++r) {
      int m = (w << 4) + (q << 2) + r;
      int n = (nf << 4) + lm;
      Cs[m * 65 + n] = acc[nf][r];
    }
  __syncthreads();
  float* dst = part + (((size_t)((ks << 4) + bt)) << 15) + co;
#pragma unroll
  for (int j = 0; j < 16; ++j) {
    int pos = (tid << 4) + j;
    int z = pos >> 8, y = (pos >> 4) & 15, xx = pos & 15;
    int m = ((z >> 2) << 4) + ((y >> 2) << 2) + (xx >> 2);
    int n = ((z & 3) << 4) + ((y & 3) << 2) + (xx & 3);
    dst[pos << 3] = Cs[m * 65 + n];
  }
}

// ---------------------------------------------------------------------------
// Fused stage 2+3, MFMA conv. 2048 blocks x 512 thr; out tile z4 x y8 x x8.
// Window: channel-last bf16 [wz 10][wy 18][wx 18][cio 8] (51.8 KB), ALL cio
// in one pass. Fill: v_pk_fma_f16 over duplicated-h1 fp16 pairs -> tanh f32
// -> bf16 pack. Conv: per (kd,kh) one mfma_f32_16x16x32_bf16 per 16 positions
// (K=32 = kw x cio); A = one ds_read_b128/lane, B preloaded from wtab2.
// ---------------------------------------------------------------------------
__global__ __launch_bounds__(512, 4) void k_stage23(
    const float* __restrict__ part, const float* __restrict__ w2,
    const float* __restrict__ b2, const float* __restrict__ b3,
    const float* __restrict__ b1, const unsigned* __restrict__ wtab2,
    float* __restrict__ out, int nsplit) {
  __shared__ __align__(16) unsigned win[10 * 18 * 18 * 4];  // 51840 B
  __shared__ __align__(16) unsigned h1d[1152];  // [uz4][uy6][ux6][ci8] dup-f16
  __shared__ __align__(16) unsigned w2p[2048];  // [cp4][kpos64][ci8] f16 pairs

  const int tid = threadIdx.x;
  const int bid = blockIdx.x;
  const int bt = bid >> 7;
  const int tile = bid & 127;
  const int tz = tile >> 4, ty = (tile >> 2) & 3, tx = tile & 3;
  const int Z0 = tz << 2, Y0 = ty << 3, X0 = tx << 3;
  const int Qz0 = (Z0 << 1) - 1, Qy0 = (Y0 << 1) - 1, Qx0 = (X0 << 1) - 1;
  const int Uz0 = (tz << 1) - 1, Uy0 = (ty << 2) - 1, Ux0 = (tx << 2) - 1;

  const int lane = tid & 63;
  const int wv = tid >> 6;        // wave 0..7
  const int n = lane & 15;        // B row (co), also A row m
  const int q = lane >> 4;        // quad: kw for A/B, m-group for D
  const int y1a = (lane >> 3) & 1, xoa = lane & 7;  // A-side m decode

  // ---- B fragments: 16 (kd,kh), 4 VGPR each, from global wtab2
  uint4 Bf[16];
#pragma unroll
  for (int kk = 0; kk < 16; ++kk)
    Bf[kk] = *(const uint4*)&wtab2[(((n << 4) + kk) << 2 | q) << 2];

  // ---- staging: h1 = tanh(sum part + b1) -> duplicated fp16 pairs
  for (int l = tid; l < 1152; l += 512) {
    int ci = l & 7;
    int c = l >> 3;
    int ux = c % 6;
    int t1 = c / 6;
    int uy = t1 % 6;
    int uz = t1 / 6;
    int gz = Uz0 + uz, gy = Uy0 + uy, gx = Ux0 + ux;
    float v = 0.f;
    if ((unsigned)gz < 16u && (unsigned)gy < 16u && (unsigned)gx < 16u) {
      const float* p =
          part + (((size_t)bt << 12) + (gz << 8) + (gy << 4) + gx) * 8 + ci;
      float s = b1[ci];
      for (int sg = 0; sg < nsplit; ++sg) s += p[(size_t)sg << 19];
      v = fast_tanh(s);
    }
    h1d[l] = pkh2(v, v);
  }
  // ---- w2 fp16 cio-pairs: [cp][kpos][ci]
  for (int l = tid; l < 2048; l += 512) {
    int ci = l & 7;
    int kpos = (l >> 3) & 63;
    int cp = l >> 9;
    float w0 = w2[((ci << 3) + (cp << 1)) * 64 + kpos];
    float w1v = w2[((ci << 3) + (cp << 1) + 1) * 64 + kpos];
    w2p[l] = pkh2(w0, w1v);
  }
  half2v b2p[4];
#pragma unroll
  for (int cp = 0; cp < 4; ++cp)
    b2p[cp] = __builtin_bit_cast(half2v, pkh2(b2[cp << 1], b2[(cp << 1) + 1]));
  __syncthreads();

  // ---- fill: 3240 positions = (wz 10) x (wy 18) x (wx 18), all 8 cio each
  for (int u = tid; u < 3240; u += 512) {
    int wz = u / 324;
    int rem = u - wz * 324;
    int wy = rem / 18;
    int wx = rem - wy * 18;
    unsigned* wrow = win + (((wz * 18 + wy) * 18 + wx) << 2);
    int qz = Qz0 + wz, qy = Qy0 + wy, qx = Qx0 + wx;
    if ((unsigned)qz < 64u && (unsigned)qy < 64u && (unsigned)qx < 64u) {
      int kpos = ((qz & 3) << 4) + ((qy & 3) << 2) + (qx & 3);
      int cell = (((((qz >> 2) - Uz0) * 6 + ((qy >> 2) - Uy0)) * 6 +
                   ((qx >> 2) - Ux0))
                  << 3);
      uint4 hA = *(const uint4*)&h1d[cell];
      uint4 hB = *(const uint4*)&h1d[cell + 4];
      float v[8];
#pragma unroll
      for (int cp = 0; cp < 4; ++cp) {
        const unsigned* wp = w2p + (cp << 9) + (kpos << 3);
        uint4 wA = *(const uint4*)wp;
        uint4 wB = *(const uint4*)(wp + 4);
        half2v a = b2p[cp];
        a = fma2(hA.x, wA.x, a);
        a = fma2(hA.y, wA.y, a);
        a = fma2(hA.z, wA.z, a);
        a = fma2(hA.w, wA.w, a);
        a = fma2(hB.x, wB.x, a);
        a = fma2(hB.y, wB.y, a);
        a = fma2(hB.z, wB.z, a);
        a = fma2(hB.w, wB.w, a);
        v[cp << 1] = fast_tanh((float)a.x);
        v[(cp << 1) + 1] = fast_tanh((float)a.y);
      }
      uint4 s;
      s.x = (unsigned)f2bf(v[0]) | ((unsigned)f2bf(v[1]) << 16);
      s.y = (unsigned)f2bf(v[2]) | ((unsigned)f2bf(v[3]) << 16);
      s.z = (unsigned)f2bf(v[4]) | ((unsigned)f2bf(v[5]) << 16);
      s.w = (unsigned)f2bf(v[6]) | ((unsigned)f2bf(v[7]) << 16);
      *(uint4*)wrow = s;
    } else {
      uint4 zz;
      zz.x = zz.y = zz.z = zz.w = 0u;
      *(uint4*)wrow = zz;
    }
  }
  __syncthreads();

  // ---- conv3 via MFMA: wave -> (z = wv>>1, yhalf = wv&1), 2 y-base tiles
  const int zq = wv >> 1, yh = wv & 1;
  const int b = bt >> 3, t8 = bt & 7;
  const float bias = (n < 4) ? b3[n] : 0.f;
#pragma unroll
  for (int t = 0; t < 2; ++t) {
    const int yb = (yh << 1) + t;
    f32x4 acc = (f32x4){0.f, 0.f, 0.f, 0.f};
#pragma unroll
    for (int kd = 0; kd < 4; ++kd) {
      const int wz = (zq << 1) + kd;
#pragma unroll
      for (int kh = 0; kh < 4; ++kh) {
        const int wy = (yb << 2) + (y1a << 1) + kh;
        const bf16x8 a = *(const bf16x8*)&win[(((wz * 18 + wy) * 18 +
                                               (xoa << 1) + q)
                                              << 2)];
        acc = __builtin_amdgcn_mfma_f32_16x16x32_bf16(
            a, __builtin_bit_cast(bf16x8, Bf[(kd << 2) + kh]), acc, 0, 0, 0);
      }
    }
    if (n < 4) {
      const int z = Z0 + zq;
#pragma unroll
      for (int reg = 0; reg < 4; ++reg) {
        int m = (q << 2) + reg;
        int y = Y0 + (yb << 1) + (m >> 3);
        int xx = X0 + (m & 7);
        out[((((((b << 2) + n) << 5 | z) << 5 | y) << 5 | xx) << 3) | t8] =
            acc[reg] + bias;
      }
    }
  }
}

extern "C" void kernel_launch(void* const* d_in, const int* in_sizes, int n_in,
                              void* d_out, int out_size, void* d_ws,
                              size_t ws_size, hipStream_t stream) {
  (void)in_sizes; (void)n_in; (void)out_size;
  const float* x = (const float*)d_in[0];
  const float* w1 = (const float*)d_in[1];
  const float* b1 = (const float*)d_in[2];
  const float* w2 = (const float*)d_in[3];
  const float* b2 = (const float*)d_in[4];
  const float* w3 = (const float*)d_in[5];
  const float* b3 = (const float*)d_in[6];
  float* out = (float*)d_out;
  float* part = (float*)d_ws;

  const size_t plane = (size_t)16 * 8 * 4096;  // floats per split (2 MB)
  int nsplit = (ws_size >= 2 * plane * 4 + 16384) ? 2 : 1;
  unsigned* wtab2 = (unsigned*)(part + (size_t)nsplit * plane);

  if (nsplit == 2)
    k_stage1<16><<<dim3(256), dim3(256), 0, stream>>>(x, w1, w3, part, wtab2);
  else
    k_stage1<32><<<dim3(128), dim3(256), 0, stream>>>(x, w1, w3, part, wtab2);
  k_stage23<<<dim3(2048), dim3(512), 0, stream>>>(part, w2, b2, b3, b1, wtab2,
                                                  out, nsplit);
}